// Round 4
// baseline (1148.636 us; speedup 1.0000x reference)
//
#include <hip/hip_runtime.h>
#include <hip/hip_bf16.h>
#include <math.h>

#define N_NODES 50000
#define N_EDGES 800000
#define DIN 41
#define H 192
#define CAP 64

// ---------------- graph prep ----------------

__global__ void k_count(const int* __restrict__ ei, int* __restrict__ cnt) {
    int e = blockIdx.x * blockDim.x + threadIdx.x;
    if (e < N_EDGES) atomicAdd(&cnt[ei[N_EDGES + e]], 1);
}

__global__ void k_dis(const int* __restrict__ cnt, float* __restrict__ dis) {
    int i = blockIdx.x * blockDim.x + threadIdx.x;
    if (i < N_NODES) dis[i] = rsqrtf((float)(cnt[i] + 1));  // +1 self-loop, deg>=1
}

__global__ void k_fill(const int* __restrict__ ei, const float* __restrict__ dis,
                       int* __restrict__ cnt2, int* __restrict__ adj_src,
                       float* __restrict__ adj_coef) {
    int e = blockIdx.x * blockDim.x + threadIdx.x;
    if (e >= N_EDGES) return;
    int s = ei[e];
    int d = ei[N_EDGES + e];
    int slot = atomicAdd(&cnt2[d], 1);
    if (slot < CAP) {
        adj_src[d * CAP + slot] = s;
        adj_coef[d * CAP + slot] = dis[s] * dis[d];
    }
}

// ---------------- input projection: h = x @ W_in + b_in ----------------

__global__ void k_in(const float* __restrict__ x, const float* __restrict__ W,
                     const float* __restrict__ b, float* __restrict__ h) {
    __shared__ float xs[DIN];
    int i = blockIdx.x;
    int j = threadIdx.x;
    if (j < DIN) xs[j] = x[i * DIN + j];
    __syncthreads();
    float acc = b[j];
#pragma unroll
    for (int k = 0; k < DIN; ++k) acc = fmaf(xs[k], W[k * H + j], acc);
    h[i * H + j] = acc;
}

// ---------------- generic K=192 GEMM: out = act(in @ W [+ b]) ----------------
// block = OUT threads, 16 nodes per block (N divisible by 16: 50000 = 3125*16)

template <int OUT, bool RELU, bool BIAS>
__global__ void k_gemm(const float* __restrict__ in, const float* __restrict__ W,
                       const float* __restrict__ bias, float* __restrict__ out) {
    __shared__ float hs[16 * H];
    const int tile = blockIdx.x;
    const int tid = threadIdx.x;
    const float* src = in + (size_t)tile * 16 * H;
    for (int idx = tid; idx < 16 * H; idx += OUT) hs[idx] = src[idx];
    __syncthreads();

    float acc[16];
#pragma unroll
    for (int i = 0; i < 16; ++i) {
        if (BIAS) acc[i] = bias[tid]; else acc[i] = 0.f;
    }

    for (int k4 = 0; k4 < H / 4; ++k4) {
        const int k = k4 * 4;
        float w0 = W[(k + 0) * OUT + tid];
        float w1 = W[(k + 1) * OUT + tid];
        float w2 = W[(k + 2) * OUT + tid];
        float w3 = W[(k + 3) * OUT + tid];
#pragma unroll
        for (int i = 0; i < 16; ++i) {
            float4 hv = *(const float4*)(&hs[i * H + k]);
            acc[i] = fmaf(hv.x, w0, acc[i]);
            acc[i] = fmaf(hv.y, w1, acc[i]);
            acc[i] = fmaf(hv.z, w2, acc[i]);
            acc[i] = fmaf(hv.w, w3, acc[i]);
        }
    }
#pragma unroll
    for (int i = 0; i < 16; ++i) {
        float v = acc[i];
        if (RELU) v = fmaxf(v, 0.f);
        out[((size_t)tile * 16 + i) * OUT + tid] = v;
    }
}

// ---------------- aggregation: h += relu(sum coef*m[src] + selfc*m[i] + bc) ----------------
// one wave (64 lanes) per node; lane covers j, j+64, j+128

__global__ void k_agg(const float* __restrict__ m, float* __restrict__ h,
                      const int* __restrict__ adj_src, const float* __restrict__ adj_coef,
                      const int* __restrict__ cnt, const float* __restrict__ dis,
                      const float* __restrict__ bc) {
    int gid = blockIdx.x * blockDim.x + threadIdx.x;
    int i = gid >> 6;
    int lane = threadIdx.x & 63;
    if (i >= N_NODES) return;

    float disi = dis[i];
    float selfc = disi * disi;
    const float* mi = m + (size_t)i * H;
    float a0 = selfc * mi[lane];
    float a1 = selfc * mi[lane + 64];
    float a2 = selfc * mi[lane + 128];

    int c = cnt[i];
    if (c > CAP) c = CAP;
    const int* as = adj_src + (size_t)i * CAP;
    const float* ac = adj_coef + (size_t)i * CAP;
    for (int e = 0; e < c; ++e) {
        int s = as[e];
        float cf = ac[e];
        const float* ms = m + (size_t)s * H;
        a0 = fmaf(cf, ms[lane], a0);
        a1 = fmaf(cf, ms[lane + 64], a1);
        a2 = fmaf(cf, ms[lane + 128], a2);
    }

    size_t base = (size_t)i * H;
    h[base + lane]       += fmaxf(a0 + bc[lane], 0.f);
    h[base + lane + 64]  += fmaxf(a1 + bc[lane + 64], 0.f);
    h[base + lane + 128] += fmaxf(a2 + bc[lane + 128], 0.f);
}

// ---------------- final: pos head tail + radius head tail + normalize ----------------
// one wave per node

__global__ void k_final(const float* __restrict__ p2, const float* __restrict__ r1,
                        const float* __restrict__ Wp3, const float* __restrict__ bp3,
                        const float* __restrict__ Wr2, const float* __restrict__ br2,
                        float* __restrict__ out) {
    int gid = blockIdx.x * blockDim.x + threadIdx.x;
    int i = gid >> 6;
    int lane = threadIdx.x & 63;
    if (i >= N_NODES) return;

    float s0 = 0.f, s1 = 0.f, sr = 0.f;
    for (int k = lane; k < 96; k += 64) {
        float pv = p2[(size_t)i * 96 + k];
        s0 = fmaf(pv, Wp3[k * 2 + 0], s0);
        s1 = fmaf(pv, Wp3[k * 2 + 1], s1);
        float rv = r1[(size_t)i * 96 + k];
        sr = fmaf(rv, Wr2[k], sr);
    }
#pragma unroll
    for (int off = 32; off > 0; off >>= 1) {
        s0 += __shfl_xor(s0, off);
        s1 += __shfl_xor(s1, off);
        sr += __shfl_xor(sr, off);
    }
    if (lane == 0) {
        s0 += bp3[0];
        s1 += bp3[1];
        float rad = 1.f / (1.f + expf(-(sr + br2[0])));
        float norm = sqrtf(s0 * s0 + s1 * s1 + 1e-8f);
        float inv = rad / norm;
        out[(size_t)i * 2 + 0] = s0 * inv;
        out[(size_t)i * 2 + 1] = s1 * inv;
    }
}

// ---------------- launch ----------------

extern "C" void kernel_launch(void* const* d_in, const int* in_sizes, int n_in,
                              void* d_out, int out_size, void* d_ws, size_t ws_size,
                              hipStream_t stream) {
    (void)in_sizes; (void)n_in; (void)out_size; (void)ws_size;

    const float* x    = (const float*)d_in[0];
    const int*   ei   = (const int*)d_in[1];
    const float* W_in = (const float*)d_in[2];
    const float* b_in = (const float*)d_in[3];
    const float* Wc   = (const float*)d_in[4];
    const float* bc   = (const float*)d_in[5];
    const float* Wp1  = (const float*)d_in[6];
    const float* bp1  = (const float*)d_in[7];
    const float* Wp2  = (const float*)d_in[8];
    const float* bp2  = (const float*)d_in[9];
    const float* Wp3  = (const float*)d_in[10];
    const float* bp3  = (const float*)d_in[11];
    const float* Wr1  = (const float*)d_in[12];
    const float* br1  = (const float*)d_in[13];
    const float* Wr2  = (const float*)d_in[14];
    const float* br2  = (const float*)d_in[15];
    float* out = (float*)d_out;

    char* ws = (char*)d_ws;
    // byte offsets (all 16B aligned)
    float* h        = (float*)(ws + 0);           // 50000*192*4 = 38,400,000
    float* m        = (float*)(ws + 38400000);    // 38,400,000
    float* p2buf    = (float*)(ws + 76800000);    // 50000*96*4 = 19,200,000
    float* r1buf    = (float*)(ws + 96000000);    // 19,200,000
    float* dis      = (float*)(ws + 115200000);   // 200,000
    int*   cnt      = (int*)  (ws + 115400000);   // 200,000
    int*   cnt2     = (int*)  (ws + 115600000);   // 200,000
    int*   adj_src  = (int*)  (ws + 115800000);   // 50000*64*4 = 12,800,000
    float* adj_coef = (float*)(ws + 128600000);   // 12,800,000
    // total 141,400,000 bytes

    // zero the two counter arrays (ws is poisoned before every call)
    hipMemsetAsync(cnt, 0, 400000, stream);  // covers cnt + cnt2 (adjacent)

    const int EB = (N_EDGES + 255) / 256;
    const int NB = (N_NODES + 255) / 256;

    k_count<<<EB, 256, 0, stream>>>(ei, cnt);
    k_dis<<<NB, 256, 0, stream>>>(cnt, dis);
    k_fill<<<EB, 256, 0, stream>>>(ei, dis, cnt2, adj_src, adj_coef);

    k_in<<<N_NODES, H, 0, stream>>>(x, W_in, b_in, h);

    for (int l = 0; l < 4; ++l) {
        k_gemm<H, false, false><<<N_NODES / 16, H, 0, stream>>>(h, Wc + (size_t)l * H * H, nullptr, m);
        k_agg<<<N_NODES / 4, 256, 0, stream>>>(m, h, adj_src, adj_coef, cnt, dis, bc + (size_t)l * H);
    }

    // heads
    k_gemm<H, true, true><<<N_NODES / 16, H, 0, stream>>>(h, Wp1, bp1, m);        // p1 (reuse m)
    k_gemm<96, true, true><<<N_NODES / 16, 96, 0, stream>>>(m, Wp2, bp2, p2buf);  // p2
    k_gemm<96, true, true><<<N_NODES / 16, 96, 0, stream>>>(h, Wr1, br1, r1buf);  // r1

    k_final<<<N_NODES / 4, 256, 0, stream>>>(p2buf, r1buf, Wp3, bp3, Wr2, br2, out);
}